// Round 4
// baseline (270.455 us; speedup 1.0000x reference)
//
#include <hip/hip_runtime.h>
#include <hip/hip_bf16.h>

// Swin shifted-window attention, fused, register-resident.
// B=64, H=W=56, DIM=128, 4 heads, WS=7. 1 block = 1 window (4096), wave = head.
// fp32 global I/O; bf16 16x16x32 MFMA; C-tiles chain into next-MFMA operands
// in-lane (paired-tile packing), mask applied via one-hot MFMA chunk (+256 trick).

#define NTOK 49
#define QS (0.08838834764831844f * 1.4426950408889634f)  // 128^-0.5 * log2(e)

typedef __bf16 bf16x8 __attribute__((ext_vector_type(8)));
typedef __bf16 bf16x2 __attribute__((ext_vector_type(2)));
typedef float  f32x4  __attribute__((ext_vector_type(4)));
typedef unsigned int u32x4 __attribute__((ext_vector_type(4)));

__device__ __forceinline__ f32x4 mfma_bf16(bf16x8 a, bf16x8 b, f32x4 c) {
  return __builtin_amdgcn_mfma_f32_16x16x32_bf16(a, b, c, 0, 0, 0);
}

__device__ __forceinline__ unsigned int pack2(float lo, float hi) {
  bf16x2 t; t[0] = (__bf16)lo; t[1] = (__bf16)hi;
  return __builtin_bit_cast(unsigned int, t);
}

__device__ __forceinline__ bf16x8 cvt8(f32x4 a, f32x4 b) {
  bf16x8 r;
#pragma unroll
  for (int j = 0; j < 4; ++j) { r[j] = (__bf16)a[j]; r[4 + j] = (__bf16)b[j]; }
  return r;
}

// region id for the shifted-window mask, computed from window coords.
__device__ __forceinline__ int regid(int t, int wh, int ww) {
  int i = t / 7;
  int j = t - i * 7;
  int rh = (wh == 7) ? ((i < 4) ? 1 : 2) : 0;
  int rw = (ww == 7) ? ((j < 4) ? 1 : 2) : 0;
  return rh * 3 + rw;
}

// Repack [K x NCOL] row-major fp32 weight into bf16 MFMA frag order; ctg<scale_below
// column-groups get *scale (folds SCALE*log2e into q-weights).
__global__ void repack_w(const float* __restrict__ w, ushort* __restrict__ packed,
                         int ncol, int scale_below, float scale) {
  int ctg  = blockIdx.x;
  int kt   = threadIdx.x >> 6;
  int lane = threadIdx.x & 63;
  int col  = ctg * 16 + (lane & 15);
  int k0   = kt * 32 + (lane >> 4) * 8;
  float s  = (ctg < scale_below) ? scale : 1.0f;
  ushort* dst = packed + (size_t)((ctg * 4 + kt) * 64 + lane) * 8;
#pragma unroll
  for (int j = 0; j < 8; ++j) {
    __bf16 h = (__bf16)(w[(size_t)(k0 + j) * ncol + col] * s);
    dst[j] = __builtin_bit_cast(ushort, h);
  }
}

__global__ __launch_bounds__(256, 3)
void swin_fused(const float* __restrict__ x,
                const float* __restrict__ qkv_b,
                const float* __restrict__ proj_b,
                const ushort* __restrict__ pqkv,
                const ushort* __restrict__ pproj,
                float* __restrict__ out)
{
  __shared__ alignas(16) ushort ao[64 * 136];   // 17408 B, only cross-wave buffer

  const int wid = blockIdx.x;
  const int b   = wid >> 6;
  const int wh  = (wid >> 3) & 7;
  const int ww  = wid & 7;
  const int tid  = threadIdx.x;
  const int wave = tid >> 6;   // = head
  const int lane = tid & 63;
  const int c    = lane & 15;
  const int g    = lane >> 4;
  const f32x4 zf = {0.f, 0.f, 0.f, 0.f};

  // ---- Phase 1: x fragments (idx=token=nt*16+c, kelem=dim) ----
  bf16x8 xf[4][4];
#pragma unroll
  for (int nt = 0; nt < 4; ++nt) {
    int token = nt * 16 + c;
    bool valid = token < NTOK;
    int tc = valid ? token : 0;
    int i = tc / 7;
    int j = tc - i * 7;
    int gh = wh * 7 + i + 3; if (gh >= 56) gh -= 56;
    int gw = ww * 7 + j + 3; if (gw >= 56) gw -= 56;
    const float* src = x + (((size_t)((b * 56 + gh) * 56 + gw)) << 7) + g * 8;
#pragma unroll
    for (int kt = 0; kt < 4; ++kt) {
      f32x4 lo = *reinterpret_cast<const f32x4*>(src + kt * 32);
      f32x4 hi = *reinterpret_cast<const f32x4*>(src + kt * 32 + 4);
      bf16x8 v = cvt8(lo, hi);
      xf[nt][kt] = valid ? v : bf16x8{};
    }
  }

  // ---- Phase 2: k^T, q^T, v GEMMs; pack C-tiles straight into next-op frags ----
  bf16x8 kf[4], qf[4], vf[2][2];

#pragma unroll
  for (int o = 0; o < 2; ++o) {   // o=0: k, o=1: q  (transposed: C = [hd][tok])
    f32x4 qc[2][4];
#pragma unroll
    for (int mt = 0; mt < 2; ++mt)
#pragma unroll
      for (int nt = 0; nt < 4; ++nt) qc[mt][nt] = zf;
#pragma unroll
    for (int kt = 0; kt < 4; ++kt) {
      bf16x8 w0 = *reinterpret_cast<const bf16x8*>(
          pqkv + (size_t)((((o ? 0 : 8) + wave * 2 + 0) * 4 + kt) * 64 + lane) * 8);
      bf16x8 w1 = *reinterpret_cast<const bf16x8*>(
          pqkv + (size_t)((((o ? 0 : 8) + wave * 2 + 1) * 4 + kt) * 64 + lane) * 8);
#pragma unroll
      for (int nt = 0; nt < 4; ++nt) {
        qc[0][nt] = mfma_bf16(w0, xf[nt][kt], qc[0][nt]);
        qc[1][nt] = mfma_bf16(w1, xf[nt][kt], qc[1][nt]);
      }
    }
    float bscale = o ? QS : 1.0f;
    int bbase = (o ? 0 : 128) + wave * 32;
#pragma unroll
    for (int mt = 0; mt < 2; ++mt)
#pragma unroll
      for (int r = 0; r < 4; ++r) {
        float bv = qkv_b[bbase + mt * 16 + g * 4 + r] * bscale;
#pragma unroll
        for (int nt = 0; nt < 4; ++nt) qc[mt][nt][r] += bv;
      }
    // pack: frag kelem g*8+j -> hd: j=0..3 from mt0 (hd g*4+j), j=4..7 from mt1.
#pragma unroll
    for (int t = 0; t < 4; ++t) {
      u32x4 u;
      u[0] = pack2(qc[0][t][0], qc[0][t][1]);
      u[1] = pack2(qc[0][t][2], qc[0][t][3]);
      u[2] = pack2(qc[1][t][0], qc[1][t][1]);
      u[3] = pack2(qc[1][t][2], qc[1][t][3]);
      if (o) qf[t] = __builtin_bit_cast(bf16x8, u);
      else   kf[t] = __builtin_bit_cast(bf16x8, u);
    }
  }

  {  // v (normal orientation: C = [tok][hd]); frag = V^T A-operand for PV
    f32x4 vc[4][2];
#pragma unroll
    for (int mt = 0; mt < 4; ++mt) { vc[mt][0] = zf; vc[mt][1] = zf; }
#pragma unroll
    for (int kt = 0; kt < 4; ++kt) {
      bf16x8 w0 = *reinterpret_cast<const bf16x8*>(
          pqkv + (size_t)(((16 + wave * 2 + 0) * 4 + kt) * 64 + lane) * 8);
      bf16x8 w1 = *reinterpret_cast<const bf16x8*>(
          pqkv + (size_t)(((16 + wave * 2 + 1) * 4 + kt) * 64 + lane) * 8);
#pragma unroll
      for (int mt = 0; mt < 4; ++mt) {
        vc[mt][0] = mfma_bf16(xf[mt][kt], w0, vc[mt][0]);
        vc[mt][1] = mfma_bf16(xf[mt][kt], w1, vc[mt][1]);
      }
    }
    float bv0 = qkv_b[256 + wave * 32 + c];
    float bv1 = qkv_b[256 + wave * 32 + 16 + c];
#pragma unroll
    for (int mt = 0; mt < 4; ++mt)
#pragma unroll
      for (int r = 0; r < 4; ++r) { vc[mt][0][r] += bv0; vc[mt][1][r] += bv1; }
#pragma unroll
    for (int kt = 0; kt < 2; ++kt)
#pragma unroll
      for (int nv = 0; nv < 2; ++nv) {
        u32x4 u;
        u[0] = pack2(vc[2 * kt][nv][0], vc[2 * kt][nv][1]);
        u[1] = pack2(vc[2 * kt][nv][2], vc[2 * kt][nv][3]);
        u[2] = pack2(vc[2 * kt + 1][nv][0], vc[2 * kt + 1][nv][1]);
        u[3] = pack2(vc[2 * kt + 1][nv][2], vc[2 * kt + 1][nv][3]);
        vf[kt][nv] = __builtin_bit_cast(bf16x8, u);
      }
  }

  // ---- Mask frags: one-hot region, value 16 (16*16=256 exact in bf16/f32) ----
  // kelem g*8+j (j=0..3) encodes region g*4+j; padded tokens -> no match.
  bf16x8 mk[4];
#pragma unroll
  for (int t = 0; t < 4; ++t) {
    int tok = t * 16 + c;
    int rk = (tok < NTOK) ? regid(tok, wh, ww) : 99;
    int d = rk - g * 4;
    unsigned long long mm =
        ((unsigned)d < 4u) ? (0x4180ull << (d * 16)) : 0ull;  // bf16 16.0
    u32x4 u = {(unsigned int)mm, (unsigned int)(mm >> 32), 0u, 0u};
    mk[t] = __builtin_bit_cast(bf16x8, u);
  }

  // ---- S^T = mask-mfma + K·Q^T mfma; softmax over k; pack P frags ----
  bf16x8 ppf[2][4];
  float rinv[4];
#pragma unroll
  for (int n = 0; n < 4; ++n) {
    f32x4 stn[4];
#pragma unroll
    for (int m = 0; m < 4; ++m) {
      stn[m] = mfma_bf16(mk[m], mk[n], zf);         // +256 where regions match
      stn[m] = mfma_bf16(kf[m], qf[n], stn[m]);     // + raw scores (log2e units)
    }
    float mx = -1e30f;
#pragma unroll
    for (int m = 0; m < 4; ++m)
#pragma unroll
      for (int r = 0; r < 4; ++r) mx = fmaxf(mx, stn[m][r]);
    mx = fmaxf(mx, __shfl_xor(mx, 16));
    mx = fmaxf(mx, __shfl_xor(mx, 32));
    float e[4][4];
    float sm = 0.f;
#pragma unroll
    for (int m = 0; m < 4; ++m)
#pragma unroll
      for (int r = 0; r < 4; ++r) {
        float ev = exp2f(stn[m][r] - mx);   // unmatched: exp2(~-256) -> exact 0
        e[m][r] = ev;
        sm += ev;
      }
    sm += __shfl_xor(sm, 16);
    sm += __shfl_xor(sm, 32);
    rinv[n] = __fdividef(1.f, sm);
#pragma unroll
    for (int kt = 0; kt < 2; ++kt) {
      u32x4 u;
      u[0] = pack2(e[2 * kt][0], e[2 * kt][1]);
      u[1] = pack2(e[2 * kt][2], e[2 * kt][3]);
      u[2] = pack2(e[2 * kt + 1][0], e[2 * kt + 1][1]);
      u[3] = pack2(e[2 * kt + 1][2], e[2 * kt + 1][3]);
      ppf[kt][n] = __builtin_bit_cast(bf16x8, u);
    }
  }

  // ---- PV: out^T[d][q] = mfma(V^T-frag, P-frag); normalize; ao write (b64) ----
#pragma unroll
  for (int nv = 0; nv < 2; ++nv)
#pragma unroll
    for (int n = 0; n < 4; ++n) {
      f32x4 po = mfma_bf16(vf[0][nv], ppf[0][n], zf);
      po = mfma_bf16(vf[1][nv], ppf[1][n], po);
      float ri = rinv[n];
      uint2 w;
      w.x = pack2(po[0] * ri, po[1] * ri);
      w.y = pack2(po[2] * ri, po[3] * ri);
      *reinterpret_cast<uint2*>(
          &ao[(n * 16 + c) * 136 + wave * 32 + nv * 16 + g * 4]) = w;
    }
  __syncthreads();

  // ---- Proj GEMM: wave computes out cols [wave*32, wave*32+32) ----
  f32x4 acc2[4][2];
#pragma unroll
  for (int m = 0; m < 4; ++m) { acc2[m][0] = zf; acc2[m][1] = zf; }
#pragma unroll
  for (int kt = 0; kt < 4; ++kt) {
    bf16x8 b20 = *reinterpret_cast<const bf16x8*>(
        pproj + (size_t)(((wave * 2 + 0) * 4 + kt) * 64 + lane) * 8);
    bf16x8 b21 = *reinterpret_cast<const bf16x8*>(
        pproj + (size_t)(((wave * 2 + 1) * 4 + kt) * 64 + lane) * 8);
#pragma unroll
    for (int m = 0; m < 4; ++m) {
      bf16x8 af = *reinterpret_cast<const bf16x8*>(&ao[(m * 16 + c) * 136 + kt * 32 + g * 8]);
      acc2[m][0] = mfma_bf16(af, b20, acc2[m][0]);
      acc2[m][1] = mfma_bf16(af, b21, acc2[m][1]);
    }
  }
  float pb0 = proj_b[wave * 32 + c];
  float pb1 = proj_b[wave * 32 + 16 + c];

  // ---- Epilogue: reverse roll, fp32 stores ----
#pragma unroll
  for (int m = 0; m < 4; ++m)
#pragma unroll
    for (int r = 0; r < 4; ++r) {
      int token = m * 16 + g * 4 + r;
      if (token < NTOK) {
        int i = token / 7;
        int j = token - i * 7;
        int oh = wh * 7 + i + 3; if (oh >= 56) oh -= 56;
        int ow = ww * 7 + j + 3; if (ow >= 56) ow -= 56;
        float* dst = out + (((size_t)((b * 56 + oh) * 56 + ow)) << 7) + wave * 32;
        dst[c]      = acc2[m][0][r] + pb0;
        dst[16 + c] = acc2[m][1][r] + pb1;
      }
    }
}

extern "C" void kernel_launch(void* const* d_in, const int* in_sizes, int n_in,
                              void* d_out, int out_size, void* d_ws, size_t ws_size,
                              hipStream_t stream) {
  const float* x      = (const float*)d_in[0];
  const float* qkv_w  = (const float*)d_in[1];
  const float* qkv_b  = (const float*)d_in[2];
  const float* proj_w = (const float*)d_in[3];
  const float* proj_b = (const float*)d_in[4];
  float* out = (float*)d_out;

  ushort* pqkv  = (ushort*)d_ws;            // 24*4*64*8 = 49152 shorts (96 KiB)
  ushort* pproj = pqkv + 49152;             //  8*4*64*8 = 16384 shorts (32 KiB)

  repack_w<<<24, 256, 0, stream>>>(qkv_w, pqkv, 384, 8, QS);   // scale q-cols
  repack_w<<<8, 256, 0, stream>>>(proj_w, pproj, 128, 0, 1.0f);
  swin_fused<<<4096, 256, 0, stream>>>(x, qkv_b, proj_b, pqkv, pproj, out);
}

// Round 7
// 245.496 us; speedup vs baseline: 1.1017x; 1.1017x over previous
//
#include <hip/hip_runtime.h>
#include <hip/hip_bf16.h>

// Swin shifted-window attention, fused. B=64, H=W=56, DIM=128, 4 heads, WS=7.
// 1 block = 1 window (4096), wave = head. fp32 global I/O; bf16 16x16x32 MFMA.
// x staged once per block in LDS (swizzled chunk layout); C-tiles chain into
// next-MFMA operands in-lane; mask via one-hot MFMA chunk (+256 trick).

#define NTOK 49
#define QS (0.08838834764831844f * 1.4426950408889634f)  // 128^-0.5 * log2(e)

typedef __bf16 bf16x8 __attribute__((ext_vector_type(8)));
typedef __bf16 bf16x2 __attribute__((ext_vector_type(2)));
typedef float  f32x4  __attribute__((ext_vector_type(4)));
typedef unsigned int u32x4 __attribute__((ext_vector_type(4)));

__device__ __forceinline__ f32x4 mfma_bf16(bf16x8 a, bf16x8 b, f32x4 c) {
  return __builtin_amdgcn_mfma_f32_16x16x32_bf16(a, b, c, 0, 0, 0);
}

__device__ __forceinline__ unsigned int pack2(float lo, float hi) {
  bf16x2 t; t[0] = (__bf16)lo; t[1] = (__bf16)hi;
  return __builtin_bit_cast(unsigned int, t);
}

__device__ __forceinline__ bf16x8 cvt8(f32x4 a, f32x4 b) {
  bf16x8 r;
#pragma unroll
  for (int j = 0; j < 4; ++j) { r[j] = (__bf16)a[j]; r[4 + j] = (__bf16)b[j]; }
  return r;
}

// region id for the shifted-window mask, computed from window coords.
__device__ __forceinline__ int regid(int t, int wh, int ww) {
  int i = t / 7;
  int j = t - i * 7;
  int rh = (wh == 7) ? ((i < 4) ? 1 : 2) : 0;
  int rw = (ww == 7) ? ((j < 4) ? 1 : 2) : 0;
  return rh * 3 + rw;
}

// x-stage LDS addressing: cell = chunk*64 + tok (8 shorts each), swizzle XOR on
// byte bits 6:5 with (tok>>3 ^ chunk)&3 -> frag reads 2-way (free), writes 4-way.
__device__ __forceinline__ int xaddr(int tok, int chunk) {
  int cell = chunk * 64 + tok;
  int sw = (((tok >> 3) ^ chunk) & 3) << 4;   // in shorts
  return (cell * 8) ^ sw;
}

// Repack [K x NCOL] row-major fp32 weight into bf16 MFMA frag order; ctg<scale_below
// column-groups get *scale (folds SCALE*log2e into q-weights).
__global__ void repack_w(const float* __restrict__ w, ushort* __restrict__ packed,
                         int ncol, int scale_below, float scale) {
  int ctg  = blockIdx.x;
  int kt   = threadIdx.x >> 6;
  int lane = threadIdx.x & 63;
  int col  = ctg * 16 + (lane & 15);
  int k0   = kt * 32 + (lane >> 4) * 8;
  float s  = (ctg < scale_below) ? scale : 1.0f;
  ushort* dst = packed + (size_t)((ctg * 4 + kt) * 64 + lane) * 8;
#pragma unroll
  for (int j = 0; j < 8; ++j) {
    __bf16 h = (__bf16)(w[(size_t)(k0 + j) * ncol + col] * s);
    dst[j] = __builtin_bit_cast(ushort, h);
  }
}

__global__ __launch_bounds__(256, 4)
void swin_fused(const float* __restrict__ x,
                const float* __restrict__ qkv_b,
                const float* __restrict__ proj_b,
                const ushort* __restrict__ pqkv,
                const ushort* __restrict__ pproj,
                float* __restrict__ out)
{
  // union: x-stage (8192 shorts, phases 0-2) / ao (8704 shorts, after barrier)
  __shared__ alignas(16) ushort lds[8704];   // 17408 B
  ushort* const xs = lds;
  ushort* const ao = lds;

  const int wid = blockIdx.x;
  const int b   = wid >> 6;
  const int wh  = (wid >> 3) & 7;
  const int ww  = wid & 7;
  const int tid  = threadIdx.x;
  const int wave = tid >> 6;   // = head
  const int lane = tid & 63;
  const int c    = lane & 15;
  const int g    = lane >> 4;
  const f32x4 zf = {0.f, 0.f, 0.f, 0.f};

  // ---- Phase 0: cooperative stage x -> LDS (coalesced 512B/row) ----
  {
    int chunk = tid & 15;
    int tokb  = tid >> 4;
#pragma unroll
    for (int it = 0; it < 4; ++it) {
      int tok = tokb + it * 16;
      bool valid = tok < NTOK;
      int tc = valid ? tok : 0;
      int ti = tc / 7;
      int tj = tc - ti * 7;
      int gh = wh * 7 + ti + 3; if (gh >= 56) gh -= 56;
      int gw = ww * 7 + tj + 3; if (gw >= 56) gw -= 56;
      const float* src = x + (((size_t)((b * 56 + gh) * 56 + gw)) << 7) + chunk * 8;
      f32x4 lo = *reinterpret_cast<const f32x4*>(src);
      f32x4 hi = *reinterpret_cast<const f32x4*>(src + 4);
      bf16x8 v = cvt8(lo, hi);
      if (!valid) v = bf16x8{};
      *reinterpret_cast<bf16x8*>(&xs[xaddr(tok, chunk)]) = v;
    }
  }
  __syncthreads();

  // ---- Phase 1: k^T, q^T, v GEMMs; pack C-tiles straight into next-op frags ----
  bf16x8 kf[4], qf[4], vf[2][2];

#pragma unroll
  for (int o = 0; o < 2; ++o) {   // o=0: k, o=1: q  (transposed: C = [hd][tok])
    f32x4 qc[2][4];
#pragma unroll
    for (int mt = 0; mt < 2; ++mt)
#pragma unroll
      for (int nt = 0; nt < 4; ++nt) qc[mt][nt] = zf;
#pragma unroll
    for (int kt = 0; kt < 4; ++kt) {
      bf16x8 w0 = *reinterpret_cast<const bf16x8*>(
          pqkv + (size_t)((((o ? 0 : 8) + wave * 2 + 0) * 4 + kt) * 64 + lane) * 8);
      bf16x8 w1 = *reinterpret_cast<const bf16x8*>(
          pqkv + (size_t)((((o ? 0 : 8) + wave * 2 + 1) * 4 + kt) * 64 + lane) * 8);
#pragma unroll
      for (int nt = 0; nt < 4; ++nt) {
        bf16x8 xn = *reinterpret_cast<const bf16x8*>(&xs[xaddr(nt * 16 + c, kt * 4 + g)]);
        qc[0][nt] = mfma_bf16(w0, xn, qc[0][nt]);
        qc[1][nt] = mfma_bf16(w1, xn, qc[1][nt]);
      }
    }
    float bscale = o ? QS : 1.0f;
    int bbase = (o ? 0 : 128) + wave * 32;
#pragma unroll
    for (int mt = 0; mt < 2; ++mt)
#pragma unroll
      for (int r = 0; r < 4; ++r) {
        float bv = qkv_b[bbase + mt * 16 + g * 4 + r] * bscale;
#pragma unroll
        for (int nt = 0; nt < 4; ++nt) qc[mt][nt][r] += bv;
      }
    // pack: frag kelem g*8+j -> hd: j=0..3 from mt0 (hd g*4+j), j=4..7 from mt1.
#pragma unroll
    for (int t = 0; t < 4; ++t) {
      u32x4 u;
      u[0] = pack2(qc[0][t][0], qc[0][t][1]);
      u[1] = pack2(qc[0][t][2], qc[0][t][3]);
      u[2] = pack2(qc[1][t][0], qc[1][t][1]);
      u[3] = pack2(qc[1][t][2], qc[1][t][3]);
      if (o) qf[t] = __builtin_bit_cast(bf16x8, u);
      else   kf[t] = __builtin_bit_cast(bf16x8, u);
    }
  }

  {  // v (normal orientation: C = [tok][hd]); frag = V^T A-operand for PV
    f32x4 vc[4][2];
#pragma unroll
    for (int mt = 0; mt < 4; ++mt) { vc[mt][0] = zf; vc[mt][1] = zf; }
#pragma unroll
    for (int kt = 0; kt < 4; ++kt) {
      bf16x8 w0 = *reinterpret_cast<const bf16x8*>(
          pqkv + (size_t)(((16 + wave * 2 + 0) * 4 + kt) * 64 + lane) * 8);
      bf16x8 w1 = *reinterpret_cast<const bf16x8*>(
          pqkv + (size_t)(((16 + wave * 2 + 1) * 4 + kt) * 64 + lane) * 8);
#pragma unroll
      for (int mt = 0; mt < 4; ++mt) {
        bf16x8 xn = *reinterpret_cast<const bf16x8*>(&xs[xaddr(mt * 16 + c, kt * 4 + g)]);
        vc[mt][0] = mfma_bf16(xn, w0, vc[mt][0]);
        vc[mt][1] = mfma_bf16(xn, w1, vc[mt][1]);
      }
    }
    float bv0 = qkv_b[256 + wave * 32 + c];
    float bv1 = qkv_b[256 + wave * 32 + 16 + c];
#pragma unroll
    for (int mt = 0; mt < 4; ++mt)
#pragma unroll
      for (int r = 0; r < 4; ++r) { vc[mt][0][r] += bv0; vc[mt][1][r] += bv1; }
#pragma unroll
    for (int kt = 0; kt < 2; ++kt)
#pragma unroll
      for (int nv = 0; nv < 2; ++nv) {
        u32x4 u;
        u[0] = pack2(vc[2 * kt][nv][0], vc[2 * kt][nv][1]);
        u[1] = pack2(vc[2 * kt][nv][2], vc[2 * kt][nv][3]);
        u[2] = pack2(vc[2 * kt + 1][nv][0], vc[2 * kt + 1][nv][1]);
        u[3] = pack2(vc[2 * kt + 1][nv][2], vc[2 * kt + 1][nv][3]);
        vf[kt][nv] = __builtin_bit_cast(bf16x8, u);
      }
  }
  __syncthreads();   // all waves done reading xs; ao may overwrite it below

  // ---- Mask frags: one-hot region, value 16 (16*16=256 exact in bf16/f32) ----
  bf16x8 mk[4];
#pragma unroll
  for (int t = 0; t < 4; ++t) {
    int tok = t * 16 + c;
    int rk = (tok < NTOK) ? regid(tok, wh, ww) : 99;
    int d = rk - g * 4;
    unsigned long long mm =
        ((unsigned)d < 4u) ? (0x4180ull << (d * 16)) : 0ull;  // bf16 16.0
    u32x4 u = {(unsigned int)mm, (unsigned int)(mm >> 32), 0u, 0u};
    mk[t] = __builtin_bit_cast(bf16x8, u);
  }

  // ---- S^T = mask-mfma + K·Q^T mfma; softmax over k; pack P frags ----
  bf16x8 ppf[2][4];
  float rinv[4];
#pragma unroll
  for (int n = 0; n < 4; ++n) {
    f32x4 stn[4];
#pragma unroll
    for (int m = 0; m < 4; ++m) {
      stn[m] = mfma_bf16(mk[m], mk[n], zf);         // +256 where regions match
      stn[m] = mfma_bf16(kf[m], qf[n], stn[m]);     // + raw scores (log2e units)
    }
    float mx = -1e30f;
#pragma unroll
    for (int m = 0; m < 4; ++m)
#pragma unroll
      for (int r = 0; r < 4; ++r) mx = fmaxf(mx, stn[m][r]);
    mx = fmaxf(mx, __shfl_xor(mx, 16));
    mx = fmaxf(mx, __shfl_xor(mx, 32));
    float e[4][4];
    float sm = 0.f;
#pragma unroll
    for (int m = 0; m < 4; ++m)
#pragma unroll
      for (int r = 0; r < 4; ++r) {
        float ev = exp2f(stn[m][r] - mx);   // unmatched: exp2(~-256) -> exact 0
        e[m][r] = ev;
        sm += ev;
      }
    sm += __shfl_xor(sm, 16);
    sm += __shfl_xor(sm, 32);
    rinv[n] = __fdividef(1.f, sm);
#pragma unroll
    for (int kt = 0; kt < 2; ++kt) {
      u32x4 u;
      u[0] = pack2(e[2 * kt][0], e[2 * kt][1]);
      u[1] = pack2(e[2 * kt][2], e[2 * kt][3]);
      u[2] = pack2(e[2 * kt + 1][0], e[2 * kt + 1][1]);
      u[3] = pack2(e[2 * kt + 1][2], e[2 * kt + 1][3]);
      ppf[kt][n] = __builtin_bit_cast(bf16x8, u);
    }
  }

  // ---- PV: out^T[d][q] = mfma(V^T-frag, P-frag); normalize; ao write (b64) ----
#pragma unroll
  for (int nv = 0; nv < 2; ++nv)
#pragma unroll
    for (int n = 0; n < 4; ++n) {
      f32x4 po = mfma_bf16(vf[0][nv], ppf[0][n], zf);
      po = mfma_bf16(vf[1][nv], ppf[1][n], po);
      float ri = rinv[n];
      uint2 w;
      w.x = pack2(po[0] * ri, po[1] * ri);
      w.y = pack2(po[2] * ri, po[3] * ri);
      *reinterpret_cast<uint2*>(
          &ao[(n * 16 + c) * 136 + wave * 32 + nv * 16 + g * 4]) = w;
    }
  __syncthreads();

  // ---- Proj GEMM: wave computes out cols [wave*32, wave*32+32) ----
  f32x4 acc2[4][2];
#pragma unroll
  for (int m = 0; m < 4; ++m) { acc2[m][0] = zf; acc2[m][1] = zf; }
#pragma unroll
  for (int kt = 0; kt < 4; ++kt) {
    bf16x8 b20 = *reinterpret_cast<const bf16x8*>(
        pproj + (size_t)(((wave * 2 + 0) * 4 + kt) * 64 + lane) * 8);
    bf16x8 b21 = *reinterpret_cast<const bf16x8*>(
        pproj + (size_t)(((wave * 2 + 1) * 4 + kt) * 64 + lane) * 8);
#pragma unroll
    for (int m = 0; m < 4; ++m) {
      bf16x8 af = *reinterpret_cast<const bf16x8*>(&ao[(m * 16 + c) * 136 + kt * 32 + g * 8]);
      acc2[m][0] = mfma_bf16(af, b20, acc2[m][0]);
      acc2[m][1] = mfma_bf16(af, b21, acc2[m][1]);
    }
  }
  float pb0 = proj_b[wave * 32 + c];
  float pb1 = proj_b[wave * 32 + 16 + c];

  // ---- Epilogue: reverse roll, fp32 stores ----
#pragma unroll
  for (int m = 0; m < 4; ++m)
#pragma unroll
    for (int r = 0; r < 4; ++r) {
      int token = m * 16 + g * 4 + r;
      if (token < NTOK) {
        int i = token / 7;
        int j = token - i * 7;
        int oh = wh * 7 + i + 3; if (oh >= 56) oh -= 56;
        int ow = ww * 7 + j + 3; if (ow >= 56) ow -= 56;
        float* dst = out + (((size_t)((b * 56 + oh) * 56 + ow)) << 7) + wave * 32;
        dst[c]      = acc2[m][0][r] + pb0;
        dst[16 + c] = acc2[m][1][r] + pb1;
      }
    }
}

extern "C" void kernel_launch(void* const* d_in, const int* in_sizes, int n_in,
                              void* d_out, int out_size, void* d_ws, size_t ws_size,
                              hipStream_t stream) {
  const float* x      = (const float*)d_in[0];
  const float* qkv_w  = (const float*)d_in[1];
  const float* qkv_b  = (const float*)d_in[2];
  const float* proj_w = (const float*)d_in[3];
  const float* proj_b = (const float*)d_in[4];
  float* out = (float*)d_out;

  ushort* pqkv  = (ushort*)d_ws;            // 24*4*64*8 = 49152 shorts (96 KiB)
  ushort* pproj = pqkv + 49152;             //  8*4*64*8 = 16384 shorts (32 KiB)

  repack_w<<<24, 256, 0, stream>>>(qkv_w, pqkv, 384, 8, QS);   // scale q-cols
  repack_w<<<8, 256, 0, stream>>>(proj_w, pproj, 128, 0, 1.0f);
  swin_fused<<<4096, 256, 0, stream>>>(x, qkv_b, proj_b, pqkv, pproj, out);
}